// Round 1
// baseline (8832.391 us; speedup 1.0000x reference)
//
#include <hip/hip_runtime.h>

#define NN 100000
#define NE 1600000
#define IND 64
#define HID 128
#define NCLS 16

// ---------------------------------------------------------------------------
// degree: deg[dst[e]] += 1
__global__ void deg_kernel(const int* __restrict__ dst, float* __restrict__ deg, int E) {
    int e = blockIdx.x * blockDim.x + threadIdx.x;
    if (e < E) atomicAdd(&deg[dst[e]], 1.0f);
}

// ---------------------------------------------------------------------------
// scatter-add rows: agg[dst[e]][:] += x[src[e]][:]
// thread = (edge, 4-dim chunk); consecutive threads share an edge -> broadcast
// index loads, contiguous float4 gathers, contiguous atomics.
template<int D>
__global__ void scatter_kernel(const float* __restrict__ x, const int* __restrict__ src,
                               const int* __restrict__ dst, float* __restrict__ agg, int E) {
    const int CH = D / 4;
    long long idx = (long long)blockIdx.x * blockDim.x + threadIdx.x;
    int e = (int)(idx / CH);
    int c = (int)(idx % CH);
    if (e >= E) return;
    int s = src[e];
    int d = dst[e];
    float4 v = *(const float4*)(x + (size_t)s * D + c * 4);
    float* p = agg + (size_t)d * D + c * 4;
    atomicAdd(p + 0, v.x);
    atomicAdd(p + 1, v.y);
    atomicAdd(p + 2, v.z);
    atomicAdd(p + 3, v.w);
}

// ---------------------------------------------------------------------------
// Fused SAGE layer: out = relu(x @ Ws + (agg/deg) @ Wn)
// Block: 256 threads = 128 cols x 2 node-halves; 16 nodes per block.
// x/agg tiles staged in LDS (inv-degree folded in at stage time).
// REDUCE=true: instead of storing h, accumulate column sums over nodes into
// out[128] (for the node-mean) via one atomic per col per block.
template<int K, bool REDUCE>
__global__ void sage_layer(const float* __restrict__ x, const float* __restrict__ agg,
                           const float* __restrict__ deg,
                           const float* __restrict__ Ws, const float* __restrict__ Wn,
                           float* __restrict__ out) {
    __shared__ float xs[16][K];
    __shared__ float ms[16][K];
    __shared__ float invd_s[16];
    __shared__ float part[128];

    const int n0 = blockIdx.x * 16;
    const int tid = threadIdx.x;

    if (tid < 16) {
        float dg = deg[n0 + tid];
        invd_s[tid] = 1.0f / fmaxf(dg, 1.0f);
    }
    __syncthreads();

    // stage x and normalized agg tiles (coalesced float4)
    const int TOT = 16 * K / 4;
    for (int i = tid; i < TOT; i += 256) {
        int node = i / (K / 4);
        int kc = i % (K / 4);
        float4 xv = *(const float4*)(x + (size_t)(n0 + node) * K + kc * 4);
        float4 av = *(const float4*)(agg + (size_t)(n0 + node) * K + kc * 4);
        float iv = invd_s[node];
        *(float4*)&xs[node][kc * 4] = xv;
        float4 mv = make_float4(av.x * iv, av.y * iv, av.z * iv, av.w * iv);
        *(float4*)&ms[node][kc * 4] = mv;
    }
    __syncthreads();

    const int col = tid & 127;
    const int half = tid >> 7;

    float acc[8];
#pragma unroll
    for (int i = 0; i < 8; i++) acc[i] = 0.0f;

    const float* __restrict__ wsp = Ws + col;
    const float* __restrict__ wnp = Wn + col;

#pragma unroll 4
    for (int k = 0; k < K; k++) {
        float wsv = wsp[(size_t)k * HID];
        float wnv = wnp[(size_t)k * HID];
#pragma unroll
        for (int i = 0; i < 8; i++) {
            int n = half * 8 + i;
            acc[i] += xs[n][k] * wsv + ms[n][k] * wnv;
        }
    }

    if (!REDUCE) {
#pragma unroll
        for (int i = 0; i < 8; i++) {
            float v = fmaxf(acc[i], 0.0f);
            out[(size_t)(n0 + half * 8 + i) * HID + col] = v;
        }
    } else {
        float s = 0.0f;
#pragma unroll
        for (int i = 0; i < 8; i++) s += fmaxf(acc[i], 0.0f);
        if (half == 0) part[col] = s;
        __syncthreads();
        if (half == 1) atomicAdd(&out[col], s + part[col]);
    }
}

// ---------------------------------------------------------------------------
// head: out[c] = 0.5 * (sigmoid((sum1/N)@Wlin1)[c] + sigmoid((sum2/N)@Wlin2)[c])
__global__ void final_kernel(const float* __restrict__ sums,
                             const float* __restrict__ Wlin1,
                             const float* __restrict__ Wlin2,
                             float* __restrict__ out) {
    __shared__ float rep[32];
    int tid = threadIdx.x;  // block = 64
    if (tid < 32) {
        int g = tid / 16;
        int c = tid % 16;
        const float* s = sums + g * HID;
        const float* W = g ? Wlin2 : Wlin1;
        float acc = 0.0f;
        const float invN = 1.0f / (float)NN;
        for (int k = 0; k < HID; k++) acc += (s[k] * invN) * W[k * NCLS + c];
        rep[tid] = 1.0f / (1.0f + expf(-acc));
    }
    __syncthreads();
    if (tid < 16) out[tid] = 0.5f * (rep[tid] + rep[16 + tid]);
}

// ---------------------------------------------------------------------------
extern "C" void kernel_launch(void* const* d_in, const int* in_sizes, int n_in,
                              void* d_out, int out_size, void* d_ws, size_t ws_size,
                              hipStream_t stream) {
    const float* feats = (const float*)d_in[0];
    const int* srcp[2] = {(const int*)d_in[1], (const int*)d_in[3]};
    const int* dstp[2] = {(const int*)d_in[2], (const int*)d_in[4]};
    const float* Ws1[2] = {(const float*)d_in[5], (const float*)d_in[10]};
    const float* Wn1[2] = {(const float*)d_in[6], (const float*)d_in[11]};
    const float* Ws2[2] = {(const float*)d_in[7], (const float*)d_in[12]};
    const float* Wn2[2] = {(const float*)d_in[8], (const float*)d_in[13]};
    const float* Wlin[2] = {(const float*)d_in[9], (const float*)d_in[14]};

    float* ws = (float*)d_ws;
    float* deg = ws;                              // NN
    float* agg = ws + NN;                         // NN*HID (layer1 uses NN*IND of it)
    float* h1 = agg + (size_t)NN * HID;           // NN*HID
    float* sums = h1 + (size_t)NN * HID;          // 2*HID

    hipMemsetAsync(sums, 0, 2 * HID * sizeof(float), stream);

    for (int g = 0; g < 2; g++) {
        hipMemsetAsync(deg, 0, NN * sizeof(float), stream);
        hipMemsetAsync(agg, 0, (size_t)NN * IND * sizeof(float), stream);

        deg_kernel<<<(NE + 255) / 256, 256, 0, stream>>>(dstp[g], deg, NE);

        {
            long long tot = (long long)NE * (IND / 4);
            int blocks = (int)((tot + 255) / 256);
            scatter_kernel<IND><<<blocks, 256, 0, stream>>>(feats, srcp[g], dstp[g], agg, NE);
        }

        sage_layer<IND, false><<<NN / 16, 256, 0, stream>>>(feats, agg, deg, Ws1[g], Wn1[g], h1);

        hipMemsetAsync(agg, 0, (size_t)NN * HID * sizeof(float), stream);

        {
            long long tot = (long long)NE * (HID / 4);
            int blocks = (int)((tot + 255) / 256);
            scatter_kernel<HID><<<blocks, 256, 0, stream>>>(h1, srcp[g], dstp[g], agg, NE);
        }

        sage_layer<HID, true><<<NN / 16, 256, 0, stream>>>(h1, agg, deg, Ws2[g], Wn2[g],
                                                           sums + g * HID);
    }

    final_kernel<<<1, 64, 0, stream>>>(sums, Wlin[0], Wlin[1], (float*)d_out);
}

// Round 2
// 1660.805 us; speedup vs baseline: 5.3181x; 5.3181x over previous
//
#include <hip/hip_runtime.h>

#define NN 100000
#define NE 1600000
#define IND 64
#define HID 128
#define NCLS 16
#define GEMMB (NN / 16)   // 6250 blocks for the fused SAGE kernels
#define RBLK 50           // tree-reduce blocks (GEMMB % RBLK == 0)

// ---------------------------------------------------------------------------
// degree histogram: cnt[dst[e]]++
__global__ void hist_kernel(const int* __restrict__ dst, int* __restrict__ cnt, int E) {
    int e = blockIdx.x * blockDim.x + threadIdx.x;
    if (e < E) atomicAdd(&cnt[dst[e]], 1);
}

// ---------------------------------------------------------------------------
// single-block exclusive scan of cnt[NN] -> rowptr (row start offsets)
__global__ void scan_kernel(const int* __restrict__ cnt, int* __restrict__ rowptr) {
    const int C = (NN + 1023) / 1024;  // 98 elements per thread
    const int tid = threadIdx.x;
    const int base = tid * C;
    const int lim = min(base + C, NN);

    int s = 0;
    for (int i = base; i < lim; i++) s += cnt[i];

    __shared__ int sums[1024];
    sums[tid] = s;
    __syncthreads();
    // Hillis-Steele inclusive scan over 1024 partials
    for (int off = 1; off < 1024; off <<= 1) {
        int v = (tid >= off) ? sums[tid - off] : 0;
        __syncthreads();
        sums[tid] += v;
        __syncthreads();
    }
    int run = (tid == 0) ? 0 : sums[tid - 1];
    for (int i = base; i < lim; i++) {
        rowptr[i] = run;
        run += cnt[i];
    }
}

// ---------------------------------------------------------------------------
// counting-sort placement: ssrc[pos] = src[e], pos = rowptr[dst[e]]++
// After this kernel rowptr[i] == END of row i (== start of row i+1).
__global__ void place_kernel(const int* __restrict__ src, const int* __restrict__ dst,
                             int* __restrict__ rowptr, int* __restrict__ ssrc, int E) {
    int e = blockIdx.x * blockDim.x + threadIdx.x;
    if (e < E) {
        int pos = atomicAdd(&rowptr[dst[e]], 1);
        ssrc[pos] = src[e];
    }
}

// ---------------------------------------------------------------------------
// Fused SAGE layer with in-block neighbor aggregation:
//   m = mean_{neighbors} x[src];  out = relu(x @ Ws + m @ Wn)
// Block: 256 threads, 16 nodes per block.
// rowend[i] = end offset of node i's edges (start = rowend[i-1], or 0).
// REDUCE=false: store h [NN][128].  REDUCE=true: write per-block column sums
// to out[blockIdx.x*128 + col] (for the node-mean readout).
template<int K, bool REDUCE>
__global__ __launch_bounds__(256) void sage_fused(
    const float* __restrict__ x, const int* __restrict__ ssrc,
    const int* __restrict__ rowend,
    const float* __restrict__ Ws, const float* __restrict__ Wn,
    float* __restrict__ out) {
    __shared__ float xs[16][K];
    __shared__ float ms[16][K];
    __shared__ float part[128];

    const int n0 = blockIdx.x * 16;
    const int tid = threadIdx.x;

    // stage self features (coalesced float4)
    const int CH = K / 4;
    for (int i = tid; i < 16 * CH; i += 256) {
        int node = i / CH;
        int kc = i % CH;
        *(float4*)&xs[node][kc * 4] =
            *(const float4*)(x + (size_t)(n0 + node) * K + kc * 4);
    }

    // aggregate neighbor means into ms: K/4 lanes per node, float4 reg acc
    const int G = K / 4;        // lanes per node (16 or 32)
    const int NPB = 256 / G;    // nodes in flight (16 or 8)
    const int lane = tid % G;
    for (int nb = tid / G; nb < 16; nb += NPB) {
        const int n = n0 + nb;
        const int start = (n == 0) ? 0 : rowend[n - 1];
        const int end = rowend[n];
        float4 acc = make_float4(0.f, 0.f, 0.f, 0.f);
        for (int e = start; e < end; e++) {
            int s = ssrc[e];
            float4 v = *(const float4*)(x + (size_t)s * K + lane * 4);
            acc.x += v.x; acc.y += v.y; acc.z += v.z; acc.w += v.w;
        }
        const float invd = 1.0f / fmaxf((float)(end - start), 1.0f);
        acc.x *= invd; acc.y *= invd; acc.z *= invd; acc.w *= invd;
        *(float4*)&ms[nb][lane * 4] = acc;
    }
    __syncthreads();

    // GEMM: 128 cols x 2 node-halves, 8 nodes per thread
    const int col = tid & 127;
    const int half = tid >> 7;

    float acc[8];
#pragma unroll
    for (int i = 0; i < 8; i++) acc[i] = 0.0f;

    const float* __restrict__ wsp = Ws + col;
    const float* __restrict__ wnp = Wn + col;

#pragma unroll 4
    for (int k = 0; k < K; k++) {
        float wsv = wsp[(size_t)k * HID];
        float wnv = wnp[(size_t)k * HID];
#pragma unroll
        for (int i = 0; i < 8; i++) {
            int n = half * 8 + i;
            acc[i] += xs[n][k] * wsv + ms[n][k] * wnv;
        }
    }

    if (!REDUCE) {
#pragma unroll
        for (int i = 0; i < 8; i++) {
            out[(size_t)(n0 + half * 8 + i) * HID + col] = fmaxf(acc[i], 0.0f);
        }
    } else {
        float s = 0.0f;
#pragma unroll
        for (int i = 0; i < 8; i++) s += fmaxf(acc[i], 0.0f);
        if (half == 0) part[col] = s;
        __syncthreads();
        if (half == 1) out[(size_t)blockIdx.x * 128 + col] = s + part[col];
    }
}

// ---------------------------------------------------------------------------
// tree-reduce stage 1: partials[GEMMB][128] (x2 graphs) -> p2[RBLK][2][128]
__global__ void reduce1_kernel(const float* __restrict__ p0, const float* __restrict__ p1,
                               float* __restrict__ p2) {
    const int bb = blockIdx.x;
    const int tid = threadIdx.x;          // 256 = 2 graphs x 128 cols
    const int g = tid >> 7;
    const int col = tid & 127;
    const float* p = g ? p1 : p0;
    const int per = GEMMB / RBLK;         // 125
    float s = 0.0f;
    for (int r = 0; r < per; r++) s += p[(size_t)(bb * per + r) * 128 + col];
    p2[(size_t)bb * 256 + tid] = s;
}

// ---------------------------------------------------------------------------
// head: rep_g = sum_nodes(h2)/N;  out = 0.5*(sigmoid(rep1@Wlin1)+sigmoid(rep2@Wlin2))
__global__ void final_kernel(const float* __restrict__ p2,
                             const float* __restrict__ Wlin1,
                             const float* __restrict__ Wlin2,
                             float* __restrict__ out) {
    __shared__ float rep[2][HID];
    __shared__ float sg[32];
    const int tid = threadIdx.x;  // 256
    float s = 0.0f;
    for (int r = 0; r < RBLK; r++) s += p2[r * 256 + tid];
    rep[tid >> 7][tid & 127] = s * (1.0f / (float)NN);
    __syncthreads();
    if (tid < 32) {
        const int g = tid / 16;
        const int c = tid % 16;
        const float* W = g ? Wlin2 : Wlin1;
        float a = 0.0f;
        for (int k = 0; k < HID; k++) a += rep[g][k] * W[k * NCLS + c];
        sg[tid] = 1.0f / (1.0f + expf(-a));
    }
    __syncthreads();
    if (tid < 16) out[tid] = 0.5f * (sg[tid] + sg[16 + tid]);
}

// ---------------------------------------------------------------------------
extern "C" void kernel_launch(void* const* d_in, const int* in_sizes, int n_in,
                              void* d_out, int out_size, void* d_ws, size_t ws_size,
                              hipStream_t stream) {
    const float* feats = (const float*)d_in[0];
    const int* srcp[2] = {(const int*)d_in[1], (const int*)d_in[3]};
    const int* dstp[2] = {(const int*)d_in[2], (const int*)d_in[4]};
    const float* Ws1[2] = {(const float*)d_in[5], (const float*)d_in[10]};
    const float* Wn1[2] = {(const float*)d_in[6], (const float*)d_in[11]};
    const float* Ws2[2] = {(const float*)d_in[7], (const float*)d_in[12]};
    const float* Wn2[2] = {(const float*)d_in[8], (const float*)d_in[13]};
    const float* Wlin[2] = {(const float*)d_in[9], (const float*)d_in[14]};

    // workspace layout (~65 MB)
    float* h1 = (float*)d_ws;                              // NN*HID
    float* part0 = h1 + (size_t)NN * HID;                  // GEMMB*128
    float* part1 = part0 + (size_t)GEMMB * 128;            // GEMMB*128
    float* p2 = part1 + (size_t)GEMMB * 128;               // RBLK*256
    int* ssrc = (int*)(p2 + RBLK * 256);                   // NE
    int* rowptr = ssrc + NE;                               // NN
    int* cnt = rowptr + NN;                                // NN
    float* partG[2] = {part0, part1};

    for (int g = 0; g < 2; g++) {
        hipMemsetAsync(cnt, 0, NN * sizeof(int), stream);
        hist_kernel<<<(NE + 255) / 256, 256, 0, stream>>>(dstp[g], cnt, NE);
        scan_kernel<<<1, 1024, 0, stream>>>(cnt, rowptr);
        place_kernel<<<(NE + 255) / 256, 256, 0, stream>>>(srcp[g], dstp[g], rowptr, ssrc, NE);

        sage_fused<IND, false><<<GEMMB, 256, 0, stream>>>(feats, ssrc, rowptr,
                                                          Ws1[g], Wn1[g], h1);
        sage_fused<HID, true><<<GEMMB, 256, 0, stream>>>(h1, ssrc, rowptr,
                                                         Ws2[g], Wn2[g], partG[g]);
    }

    reduce1_kernel<<<RBLK, 256, 0, stream>>>(part0, part1, p2);
    final_kernel<<<1, 256, 0, stream>>>(p2, Wlin[0], Wlin[1], (float*)d_out);
}

// Round 3
// 1309.256 us; speedup vs baseline: 6.7461x; 1.2685x over previous
//
#include <hip/hip_runtime.h>

#define NN 100000
#define NE 1600000
#define IND 64
#define HID 128
#define NCLS 16
#define GEMMB (NN / 16)   // 6250
#define RBLK 50

// ---------------------------------------------------------------------------
// bf16 helpers (manual RNE pack / unpack; fp32 accumulate everywhere)
__device__ __forceinline__ unsigned short f2b(float f) {
    unsigned u = __float_as_uint(f);
    return (unsigned short)((u + 0x7fffu + ((u >> 16) & 1u)) >> 16);
}
__device__ __forceinline__ float blo(unsigned u) { return __uint_as_float(u << 16); }
__device__ __forceinline__ float bhi(unsigned u) { return __uint_as_float(u & 0xffff0000u); }

__device__ __forceinline__ void bacc8(float* a, uint4 v) {
    a[0] += blo(v.x); a[1] += bhi(v.x);
    a[2] += blo(v.y); a[3] += bhi(v.y);
    a[4] += blo(v.z); a[5] += bhi(v.z);
    a[6] += blo(v.w); a[7] += bhi(v.w);
}

// ---------------------------------------------------------------------------
// fp32 -> bf16 table conversion (8 elems / thread)
__global__ void conv_kernel(const float* __restrict__ x, uint4* __restrict__ xb, int n8) {
    int i = blockIdx.x * blockDim.x + threadIdx.x;
    if (i >= n8) return;
    const float4* p = (const float4*)x + (size_t)i * 2;
    float4 a = p[0], b = p[1];
    uint4 o;
    o.x = (unsigned)f2b(a.x) | ((unsigned)f2b(a.y) << 16);
    o.y = (unsigned)f2b(a.z) | ((unsigned)f2b(a.w) << 16);
    o.z = (unsigned)f2b(b.x) | ((unsigned)f2b(b.y) << 16);
    o.w = (unsigned)f2b(b.z) | ((unsigned)f2b(b.w) << 16);
    xb[i] = o;
}

// ---------------------------------------------------------------------------
// combined degree histogram for both graphs
__global__ void hist_kernel(const int* __restrict__ d0, const int* __restrict__ d1,
                            int* __restrict__ c0, int* __restrict__ c1, int E) {
    int idx = blockIdx.x * blockDim.x + threadIdx.x;
    if (idx < E) atomicAdd(&c0[d0[idx]], 1);
    else if (idx < 2 * E) atomicAdd(&c1[d1[idx - E]], 1);
}

// ---------------------------------------------------------------------------
// per-graph exclusive scan (block 0 -> graph 0, block 1 -> graph 1)
__global__ void scan_kernel(const int* __restrict__ c0, const int* __restrict__ c1,
                            int* __restrict__ r0, int* __restrict__ r1) {
    const int* cnt = blockIdx.x ? c1 : c0;
    int* rowptr = blockIdx.x ? r1 : r0;
    const int C = (NN + 1023) / 1024;
    const int tid = threadIdx.x;
    const int base = tid * C;
    const int lim = min(base + C, NN);

    int s = 0;
    for (int i = base; i < lim; i++) s += cnt[i];

    __shared__ int sums[1024];
    sums[tid] = s;
    __syncthreads();
    for (int off = 1; off < 1024; off <<= 1) {
        int v = (tid >= off) ? sums[tid - off] : 0;
        __syncthreads();
        sums[tid] += v;
        __syncthreads();
    }
    int run = (tid == 0) ? 0 : sums[tid - 1];
    for (int i = base; i < lim; i++) {
        rowptr[i] = run;
        run += cnt[i];
    }
}

// ---------------------------------------------------------------------------
// counting-sort placement, both graphs; rowptr becomes row-END offsets
__global__ void place_kernel(const int* __restrict__ s0, const int* __restrict__ d0,
                             const int* __restrict__ s1, const int* __restrict__ d1,
                             int* __restrict__ r0, int* __restrict__ r1,
                             int* __restrict__ o0, int* __restrict__ o1, int E) {
    int idx = blockIdx.x * blockDim.x + threadIdx.x;
    const int *s, *d; int *r, *o; int e;
    if (idx < E)          { s = s0; d = d0; r = r0; o = o0; e = idx; }
    else if (idx < 2 * E) { s = s1; d = d1; r = r1; o = o1; e = idx - E; }
    else return;
    int pos = atomicAdd(&r[d[e]], 1);
    o[pos] = s[e];
}

// ---------------------------------------------------------------------------
// Fused SAGE layer. KS = input dim (64 -> layer1, 128 -> layer2).
//   layer1: self from fp32 xf, gather from bf16 xb, output h1 as bf16 (outH)
//   layer2: self+gather from bf16 xb, REDUCE -> per-block col sums (outR)
// Block: 256 threads, 16 nodes. GEMM: thread = (col pair p, node quad q);
// A-reads are wave-uniform ds_read_b128 broadcasts.
template<int KS, bool REDUCE>
__global__ __launch_bounds__(256) void sage_fused(
    const float* __restrict__ xf, const uint4* __restrict__ xb,
    const int* __restrict__ ssrc, const int* __restrict__ rowend,
    const float* __restrict__ Ws, const float* __restrict__ Wn,
    float* __restrict__ outR, unsigned* __restrict__ outH) {
    __shared__ float xms[16][2 * KS];
    __shared__ float part[4][128];

    const int tid = threadIdx.x;
    const int n0 = blockIdx.x * 16;
    const int RW = KS / 8;  // uint4 per bf16 row

    // ---- self staging (one float4/uint4 per thread) ----
    {
        int node = tid / 16, c = tid % 16;
        if constexpr (KS == IND) {
            float4 v = ((const float4*)xf)[(size_t)(n0 + node) * (KS / 4) + c];
            *(float4*)&xms[node][c * 4] = v;
        } else {
            uint4 v = xb[(size_t)(n0 + node) * RW + c];
            *(float4*)&xms[node][c * 8] = make_float4(blo(v.x), bhi(v.x), blo(v.y), bhi(v.y));
            *(float4*)&xms[node][c * 8 + 4] = make_float4(blo(v.z), bhi(v.z), blo(v.w), bhi(v.w));
        }
    }

    // ---- neighbor mean aggregation (bf16 gather, fp32 acc) ----
    if constexpr (KS == HID) {
        // 16 lanes/node, 16 nodes concurrently, edge loop unrolled x4
        const int nb = tid / 16, l = tid % 16;
        const int n = n0 + nb;
        const int start = (n == 0) ? 0 : rowend[n - 1];
        const int end = rowend[n];
        float a[8] = {0, 0, 0, 0, 0, 0, 0, 0};
        const uint4* base = xb + l;
        int e = start;
        for (; e + 4 <= end; e += 4) {
            int i0 = ssrc[e], i1 = ssrc[e + 1], i2 = ssrc[e + 2], i3 = ssrc[e + 3];
            uint4 v0 = base[(size_t)i0 * RW];
            uint4 v1 = base[(size_t)i1 * RW];
            uint4 v2 = base[(size_t)i2 * RW];
            uint4 v3 = base[(size_t)i3 * RW];
            bacc8(a, v0); bacc8(a, v1); bacc8(a, v2); bacc8(a, v3);
        }
        for (; e < end; e++) bacc8(a, base[(size_t)ssrc[e] * RW]);
        const float invd = 1.0f / fmaxf((float)(end - start), 1.0f);
        *(float4*)&xms[nb][KS + l * 8] =
            make_float4(a[0] * invd, a[1] * invd, a[2] * invd, a[3] * invd);
        *(float4*)&xms[nb][KS + l * 8 + 4] =
            make_float4(a[4] * invd, a[5] * invd, a[6] * invd, a[7] * invd);
    } else {
        // 8 lanes/node-half, 2 halves/node (even/odd edges), combine via shfl_xor(8)
        const int slot = tid / 8, l = tid % 8;
        const int nb = slot >> 1, h = slot & 1;
        const int n = n0 + nb;
        const int start = (n == 0) ? 0 : rowend[n - 1];
        const int end = rowend[n];
        float a[8] = {0, 0, 0, 0, 0, 0, 0, 0};
        const uint4* base = xb + l;
        int e = start + h;
        for (; e + 2 < end; e += 4) {  // edges e, e+2
            int i0 = ssrc[e], i1 = ssrc[e + 2];
            uint4 v0 = base[(size_t)i0 * RW];
            uint4 v1 = base[(size_t)i1 * RW];
            bacc8(a, v0); bacc8(a, v1);
        }
        if (e < end) bacc8(a, base[(size_t)ssrc[e] * RW]);
#pragma unroll
        for (int j = 0; j < 8; j++) a[j] += __shfl_xor(a[j], 8);
        if (h == 0) {
            const float invd = 1.0f / fmaxf((float)(end - start), 1.0f);
            *(float4*)&xms[nb][KS + l * 8] =
                make_float4(a[0] * invd, a[1] * invd, a[2] * invd, a[3] * invd);
            *(float4*)&xms[nb][KS + l * 8 + 4] =
                make_float4(a[4] * invd, a[5] * invd, a[6] * invd, a[7] * invd);
        }
    }
    __syncthreads();

    // ---- GEMM: out = relu([xs|ms] @ [Ws;Wn]) ----
    const int p = tid % 64;   // cols 2p, 2p+1
    const int q = tid / 64;   // nodes 4q..4q+3
    float a00 = 0, a01 = 0, a10 = 0, a11 = 0, a20 = 0, a21 = 0, a30 = 0, a31 = 0;

#pragma unroll
    for (int seg = 0; seg < 2; seg++) {
        const float* __restrict__ W = seg ? Wn : Ws;
        const int koff = seg * KS;
#pragma unroll 2
        for (int k = 0; k < KS; k += 4) {
            const float* Wk = W + (size_t)k * HID + 2 * p;
            float2 w0 = *(const float2*)(Wk);
            float2 w1 = *(const float2*)(Wk + HID);
            float2 w2 = *(const float2*)(Wk + 2 * HID);
            float2 w3 = *(const float2*)(Wk + 3 * HID);
            float4 v0 = *(const float4*)&xms[4 * q + 0][koff + k];
            float4 v1 = *(const float4*)&xms[4 * q + 1][koff + k];
            float4 v2 = *(const float4*)&xms[4 * q + 2][koff + k];
            float4 v3 = *(const float4*)&xms[4 * q + 3][koff + k];
            a00 += v0.x * w0.x + v0.y * w1.x + v0.z * w2.x + v0.w * w3.x;
            a01 += v0.x * w0.y + v0.y * w1.y + v0.z * w2.y + v0.w * w3.y;
            a10 += v1.x * w0.x + v1.y * w1.x + v1.z * w2.x + v1.w * w3.x;
            a11 += v1.x * w0.y + v1.y * w1.y + v1.z * w2.y + v1.w * w3.y;
            a20 += v2.x * w0.x + v2.y * w1.x + v2.z * w2.x + v2.w * w3.x;
            a21 += v2.x * w0.y + v2.y * w1.y + v2.z * w2.y + v2.w * w3.y;
            a30 += v3.x * w0.x + v3.y * w1.x + v3.z * w2.x + v3.w * w3.x;
            a31 += v3.x * w0.y + v3.y * w1.y + v3.z * w2.y + v3.w * w3.y;
        }
    }

    if constexpr (!REDUCE) {
        // store h as bf16 pairs: 4 B/thread/node, contiguous per node row
        float r0, r1;
        r0 = fmaxf(a00, 0.f); r1 = fmaxf(a01, 0.f);
        outH[(size_t)(n0 + 4 * q + 0) * (HID / 2) + p] = (unsigned)f2b(r0) | ((unsigned)f2b(r1) << 16);
        r0 = fmaxf(a10, 0.f); r1 = fmaxf(a11, 0.f);
        outH[(size_t)(n0 + 4 * q + 1) * (HID / 2) + p] = (unsigned)f2b(r0) | ((unsigned)f2b(r1) << 16);
        r0 = fmaxf(a20, 0.f); r1 = fmaxf(a21, 0.f);
        outH[(size_t)(n0 + 4 * q + 2) * (HID / 2) + p] = (unsigned)f2b(r0) | ((unsigned)f2b(r1) << 16);
        r0 = fmaxf(a30, 0.f); r1 = fmaxf(a31, 0.f);
        outH[(size_t)(n0 + 4 * q + 3) * (HID / 2) + p] = (unsigned)f2b(r0) | ((unsigned)f2b(r1) << 16);
    } else {
        float s0 = fmaxf(a00, 0.f) + fmaxf(a10, 0.f) + fmaxf(a20, 0.f) + fmaxf(a30, 0.f);
        float s1 = fmaxf(a01, 0.f) + fmaxf(a11, 0.f) + fmaxf(a21, 0.f) + fmaxf(a31, 0.f);
        *(float2*)&part[q][2 * p] = make_float2(s0, s1);
        __syncthreads();
        if (tid < 128) {
            float s = part[0][tid] + part[1][tid] + part[2][tid] + part[3][tid];
            outR[(size_t)blockIdx.x * 128 + tid] = s;
        }
    }
}

// ---------------------------------------------------------------------------
__global__ void reduce1_kernel(const float* __restrict__ p0, const float* __restrict__ p1,
                               float* __restrict__ p2) {
    const int bb = blockIdx.x;
    const int tid = threadIdx.x;
    const int g = tid >> 7;
    const int col = tid & 127;
    const float* p = g ? p1 : p0;
    const int per = GEMMB / RBLK;
    float s = 0.0f;
    for (int r = 0; r < per; r++) s += p[(size_t)(bb * per + r) * 128 + col];
    p2[(size_t)bb * 256 + tid] = s;
}

__global__ void final_kernel(const float* __restrict__ p2,
                             const float* __restrict__ Wlin1,
                             const float* __restrict__ Wlin2,
                             float* __restrict__ out) {
    __shared__ float rep[2][HID];
    __shared__ float sg[32];
    const int tid = threadIdx.x;
    float s = 0.0f;
    for (int r = 0; r < RBLK; r++) s += p2[r * 256 + tid];
    rep[tid >> 7][tid & 127] = s * (1.0f / (float)NN);
    __syncthreads();
    if (tid < 32) {
        const int g = tid / 16;
        const int c = tid % 16;
        const float* W = g ? Wlin2 : Wlin1;
        float a = 0.0f;
        for (int k = 0; k < HID; k++) a += rep[g][k] * W[k * NCLS + c];
        sg[tid] = 1.0f / (1.0f + expf(-a));
    }
    __syncthreads();
    if (tid < 16) out[tid] = 0.5f * (sg[tid] + sg[16 + tid]);
}

// ---------------------------------------------------------------------------
extern "C" void kernel_launch(void* const* d_in, const int* in_sizes, int n_in,
                              void* d_out, int out_size, void* d_ws, size_t ws_size,
                              hipStream_t stream) {
    const float* feats = (const float*)d_in[0];
    const int* srcp[2] = {(const int*)d_in[1], (const int*)d_in[3]};
    const int* dstp[2] = {(const int*)d_in[2], (const int*)d_in[4]};
    const float* Ws1[2] = {(const float*)d_in[5], (const float*)d_in[10]};
    const float* Wn1[2] = {(const float*)d_in[6], (const float*)d_in[11]};
    const float* Ws2[2] = {(const float*)d_in[7], (const float*)d_in[12]};
    const float* Wn2[2] = {(const float*)d_in[8], (const float*)d_in[13]};
    const float* Wlin[2] = {(const float*)d_in[9], (const float*)d_in[14]};

    // workspace layout (~58 MB), all sections 16B-aligned
    char* w = (char*)d_ws;
    uint4* fb = (uint4*)w;                 w += (size_t)NN * IND * 2;       // feats bf16
    unsigned* h1b = (unsigned*)w;          w += (size_t)NN * HID * 2;       // h1 bf16
    float* part0 = (float*)w;              w += (size_t)GEMMB * 128 * 4;
    float* part1 = (float*)w;              w += (size_t)GEMMB * 128 * 4;
    float* p2 = (float*)w;                 w += (size_t)RBLK * 256 * 4;
    int* ssrc0 = (int*)w;                  w += (size_t)NE * 4;
    int* ssrc1 = (int*)w;                  w += (size_t)NE * 4;
    int* row0 = (int*)w;                   w += (size_t)NN * 4;
    int* row1 = (int*)w;                   w += (size_t)NN * 4;
    int* cnt0 = (int*)w;                   w += (size_t)NN * 4;
    int* cnt1 = (int*)w;                   w += (size_t)NN * 4;

    // feats -> bf16 table
    conv_kernel<<<(NN * IND / 8 + 255) / 256, 256, 0, stream>>>(feats, fb, NN * IND / 8);

    // CSR build for both graphs
    hipMemsetAsync(cnt0, 0, 2 * (size_t)NN * 4, stream);  // cnt0,cnt1 adjacent
    hist_kernel<<<(2 * NE + 255) / 256, 256, 0, stream>>>(dstp[0], dstp[1], cnt0, cnt1, NE);
    scan_kernel<<<2, 1024, 0, stream>>>(cnt0, cnt1, row0, row1);
    place_kernel<<<(2 * NE + 255) / 256, 256, 0, stream>>>(
        srcp[0], dstp[0], srcp[1], dstp[1], row0, row1, ssrc0, ssrc1, NE);

    const int* ssrcg[2] = {ssrc0, ssrc1};
    const int* rowg[2] = {row0, row1};
    float* partG[2] = {part0, part1};

    for (int g = 0; g < 2; g++) {
        sage_fused<IND, false><<<GEMMB, 256, 0, stream>>>(
            feats, fb, ssrcg[g], rowg[g], Ws1[g], Wn1[g], nullptr, h1b);
        sage_fused<HID, true><<<GEMMB, 256, 0, stream>>>(
            nullptr, (const uint4*)h1b, ssrcg[g], rowg[g], Ws2[g], Wn2[g], partG[g], nullptr);
    }

    reduce1_kernel<<<RBLK, 256, 0, stream>>>(part0, part1, p2);
    final_kernel<<<1, 256, 0, stream>>>(p2, Wlin[0], Wlin[1], (float*)d_out);
}

// Round 5
// 867.212 us; speedup vs baseline: 10.1848x; 1.5097x over previous
//
#include <hip/hip_runtime.h>

#define NN 100000
#define NE 1600000
#define IND 64
#define HID 128
#define NCLS 16
#define GEMMB (NN / 16)   // 6250
#define RBLK 50
#define BK 98             // buckets (1024 nodes each, 98*1024 >= NN)
#define BW 1024           // nodes per bucket
#define EPB 2048          // edges per block in bucket hist/place
#define NBG ((NE + EPB - 1) / EPB)   // 782 blocks per graph

typedef float v2f __attribute__((ext_vector_type(2)));

// ---------------------------------------------------------------------------
// bf16 helpers
__device__ __forceinline__ unsigned short f2b(float f) {
    unsigned u = __float_as_uint(f);
    return (unsigned short)((u + 0x7fffu + ((u >> 16) & 1u)) >> 16);
}
__device__ __forceinline__ float blo(unsigned u) { return __uint_as_float(u << 16); }
__device__ __forceinline__ float bhi(unsigned u) { return __uint_as_float(u & 0xffff0000u); }

// ---------------------------------------------------------------------------
// fp8 e4m3 helpers (HW cvt if available, software fallback otherwise)
__device__ __forceinline__ float fp8_sw_unpack(unsigned b) {
    unsigned s = (b >> 7) & 1u, em = b & 0x7fu;
    return __uint_as_float((s << 31) | (em << 20)) * 0x1p+120f;
}
__device__ __forceinline__ unsigned fp8_sw_pack(float f) {
    float c = fminf(fmaxf(f, -448.f), 448.f) * 0x1p-120f;
    unsigned b = __float_as_uint(c);
    unsigned s = b >> 31; b &= 0x7fffffffu;
    b = b + 0x7ffffu + ((b >> 20) & 1u);
    unsigned em = b >> 20;
    if (em > 0x7eu) em = 0x7eu;
    return (s << 7) | em;
}

template<bool HI>
__device__ __forceinline__ unsigned pk8(float a, float b, unsigned old) {
#if __has_builtin(__builtin_amdgcn_cvt_pk_fp8_f32)
    return (unsigned)__builtin_amdgcn_cvt_pk_fp8_f32(a, b, (int)old, HI);
#else
    unsigned v = fp8_sw_pack(a) | (fp8_sw_pack(b) << 8);
    return HI ? ((old & 0x0000ffffu) | (v << 16)) : ((old & 0xffff0000u) | v);
#endif
}
template<bool HI>
__device__ __forceinline__ v2f upk8(unsigned u) {
#if __has_builtin(__builtin_amdgcn_cvt_pk_f32_fp8)
    return __builtin_amdgcn_cvt_pk_f32_fp8((int)u, HI);
#else
    unsigned x = HI ? (u >> 16) : u;
    v2f r; r.x = fp8_sw_unpack(x & 0xffu); r.y = fp8_sw_unpack((x >> 8) & 0xffu);
    return r;
#endif
}

__device__ __forceinline__ void bacc16(float* a, uint4 v) {
    v2f t;
    t = upk8<false>(v.x); a[0] += t.x;  a[1] += t.y;
    t = upk8<true>(v.x);  a[2] += t.x;  a[3] += t.y;
    t = upk8<false>(v.y); a[4] += t.x;  a[5] += t.y;
    t = upk8<true>(v.y);  a[6] += t.x;  a[7] += t.y;
    t = upk8<false>(v.z); a[8] += t.x;  a[9] += t.y;
    t = upk8<true>(v.z);  a[10] += t.x; a[11] += t.y;
    t = upk8<false>(v.w); a[12] += t.x; a[13] += t.y;
    t = upk8<true>(v.w);  a[14] += t.x; a[15] += t.y;
}

// ---------------------------------------------------------------------------
// feats fp32 -> fp8 table (4 elems / thread)
__global__ void conv8_kernel(const float4* __restrict__ x, unsigned* __restrict__ o, int n4) {
    int i = blockIdx.x * blockDim.x + threadIdx.x;
    if (i >= n4) return;
    float4 v = x[i];
    unsigned w = pk8<false>(v.x, v.y, 0u);
    w = pk8<true>(v.z, v.w, w);
    o[i] = w;
}

// ---------------------------------------------------------------------------
// bucket histogram (both graphs): bcnt[g][b] += # edges with dst in bucket b
__global__ void bucket_hist(const int* __restrict__ d0, const int* __restrict__ d1,
                            int* __restrict__ bcnt) {
    __shared__ int h[BK];
    const int bi = blockIdx.x;
    const int g = bi >= NBG;
    const int* dst = g ? d1 : d0;
    const int base = (g ? bi - NBG : bi) * EPB;
    for (int i = threadIdx.x; i < BK; i += 256) h[i] = 0;
    __syncthreads();
    for (int j = 0; j < EPB; j += 256) {
        int e = base + j + threadIdx.x;
        if (e < NE) atomicAdd(&h[dst[e] >> 10], 1);
    }
    __syncthreads();
    for (int i = threadIdx.x; i < BK; i += 256)
        if (h[i]) atomicAdd(&bcnt[g * BK + i], h[i]);
}

// ---------------------------------------------------------------------------
// tiny serial scan per graph: bucket bases (+sentinel) and place cursors
__global__ void bucket_scan(const int* __restrict__ bcnt, int* __restrict__ bbase,
                            int* __restrict__ bcur) {
    int t = threadIdx.x;
    if (t < 2) {
        int run = 0;
        for (int i = 0; i < BK; i++) {
            bbase[t * (BK + 1) + i] = run;
            bcur[t * BK + i] = run;
            run += bcnt[t * BK + i];
        }
        bbase[t * (BK + 1) + BK] = run;  // == NE
    }
}

// ---------------------------------------------------------------------------
// partition edges into bucket regions as packed pairs: src | (dst&1023)<<17
__global__ void bucket_place(const int* __restrict__ s0, const int* __restrict__ d0,
                             const int* __restrict__ s1, const int* __restrict__ d1,
                             int* __restrict__ bcur,
                             unsigned* __restrict__ p0, unsigned* __restrict__ p1) {
    __shared__ int h[BK], hb[BK];
    const int bi = blockIdx.x;
    const int g = bi >= NBG;
    const int* src = g ? s1 : s0;
    const int* dst = g ? d1 : d0;
    unsigned* pairs = g ? p1 : p0;
    const int base = (g ? bi - NBG : bi) * EPB;
    for (int i = threadIdx.x; i < BK; i += 256) h[i] = 0;
    __syncthreads();
    for (int j = 0; j < EPB; j += 256) {
        int e = base + j + threadIdx.x;
        if (e < NE) atomicAdd(&h[dst[e] >> 10], 1);
    }
    __syncthreads();
    for (int i = threadIdx.x; i < BK; i += 256) {
        hb[i] = h[i] ? atomicAdd(&bcur[g * BK + i], h[i]) : 0;
        h[i] = 0;
    }
    __syncthreads();
    for (int j = 0; j < EPB; j += 256) {
        int e = base + j + threadIdx.x;
        if (e < NE) {
            int d = dst[e];
            int b = d >> 10;
            int slot = atomicAdd(&h[b], 1);
            pairs[hb[b] + slot] = (unsigned)src[e] | ((unsigned)(d & 1023) << 17);
        }
    }
}

// ---------------------------------------------------------------------------
// one block per bucket: LDS hist over 1024 nodes, scan, write rowend + ssrc
__global__ __launch_bounds__(256) void bucket_final(
    const unsigned* __restrict__ p0, const unsigned* __restrict__ p1,
    const int* __restrict__ bbase,
    int* __restrict__ row0, int* __restrict__ row1,
    int* __restrict__ ss0, int* __restrict__ ss1) {
    __shared__ int cnt[BW];
    __shared__ int ex[BW];
    __shared__ int aux[256];
    const int bi = blockIdx.x;
    const int g = bi >= BK;
    const int b = g ? bi - BK : bi;
    const unsigned* pairs = g ? p1 : p0;
    int* rowend = g ? row1 : row0;
    int* ssrc = g ? ss1 : ss0;
    const int ebase = bbase[g * (BK + 1) + b];
    const int eend = bbase[g * (BK + 1) + b + 1];
    const int tid = threadIdx.x;

    for (int i = tid; i < BW; i += 256) cnt[i] = 0;
    __syncthreads();
    for (int e = ebase + tid; e < eend; e += 256)
        atomicAdd(&cnt[pairs[e] >> 17], 1);
    __syncthreads();

    int c0 = cnt[4 * tid], c1 = cnt[4 * tid + 1], c2 = cnt[4 * tid + 2], c3 = cnt[4 * tid + 3];
    aux[tid] = c0 + c1 + c2 + c3;
    __syncthreads();
    for (int off = 1; off < 256; off <<= 1) {
        int v = (tid >= off) ? aux[tid - off] : 0;
        __syncthreads();
        aux[tid] += v;
        __syncthreads();
    }
    int excl = tid ? aux[tid - 1] : 0;
    ex[4 * tid] = excl;
    ex[4 * tid + 1] = excl + c0;
    ex[4 * tid + 2] = excl + c0 + c1;
    ex[4 * tid + 3] = excl + c0 + c1 + c2;

    const int nodebase = b * BW + 4 * tid;
    if (nodebase + 0 < NN) rowend[nodebase + 0] = ebase + excl + c0;
    if (nodebase + 1 < NN) rowend[nodebase + 1] = ebase + excl + c0 + c1;
    if (nodebase + 2 < NN) rowend[nodebase + 2] = ebase + excl + c0 + c1 + c2;
    if (nodebase + 3 < NN) rowend[nodebase + 3] = ebase + excl + c0 + c1 + c2 + c3;
    __syncthreads();

    for (int e = ebase + tid; e < eend; e += 256) {
        unsigned pk = pairs[e];
        int dl = pk >> 17;
        int pos = ebase + atomicAdd(&ex[dl], 1);
        ssrc[pos] = (int)(pk & 0x1FFFFu);
    }
}

// ---------------------------------------------------------------------------
// Fused SAGE layer. fp8 gather table x8; self from fp32 (L1) or bf16 (L2).
template<int KS, bool REDUCE>
__global__ __launch_bounds__(256) void sage_fused(
    const float* __restrict__ xf, const unsigned* __restrict__ xbself,
    const unsigned* __restrict__ x8,
    const int* __restrict__ ssrc, const int* __restrict__ rowend,
    const float* __restrict__ Ws, const float* __restrict__ Wn,
    float* __restrict__ outR, unsigned* __restrict__ outHb, unsigned* __restrict__ outH8) {
    __shared__ float xms[16][2 * KS + 4];
    __shared__ float part[4][128];

    const int tid = threadIdx.x;
    const int n0 = blockIdx.x * 16;
    const uint4* xb4 = (const uint4*)x8;

    // ---- self staging ----
    {
        int node = tid / 16, c = tid % 16;
        if constexpr (KS == IND) {
            float4 v = ((const float4*)xf)[(size_t)(n0 + node) * 16 + c];
            *(float4*)&xms[node][c * 4] = v;
        } else {
            uint4 u = ((const uint4*)xbself)[(size_t)(n0 + node) * 16 + c];
            *(float4*)&xms[node][c * 8] = make_float4(blo(u.x), bhi(u.x), blo(u.y), bhi(u.y));
            *(float4*)&xms[node][c * 8 + 4] = make_float4(blo(u.z), bhi(u.z), blo(u.w), bhi(u.w));
        }
    }

    // ---- neighbor mean aggregation (fp8 gather, fp32 acc) ----
    {
        const int nb = tid >> 4;
        const int n = n0 + nb;
        const int start = (n == 0) ? 0 : rowend[n - 1];
        const int end = rowend[n];
        float a[16];
#pragma unroll
        for (int j = 0; j < 16; j++) a[j] = 0.0f;

        if constexpr (KS == HID) {
            const int l = tid & 7;          // uint4 index (8/row)
            const int h = (tid >> 3) & 1;   // 2 chains
            int e = start + h;
            for (; e + 2 < end; e += 4) {
                int i0 = ssrc[e], i1 = ssrc[e + 2];
                uint4 v0 = xb4[(size_t)i0 * 8 + l];
                uint4 v1 = xb4[(size_t)i1 * 8 + l];
                bacc16(a, v0);
                bacc16(a, v1);
            }
            if (e < end) bacc16(a, xb4[(size_t)ssrc[e] * 8 + l]);
#pragma unroll
            for (int j = 0; j < 16; j++) a[j] += __shfl_xor(a[j], 8);
            if (h == 0) {
                float iv = 1.0f / fmaxf((float)(end - start), 1.0f);
                *(float4*)&xms[nb][KS + l * 16 + 0] = make_float4(a[0] * iv, a[1] * iv, a[2] * iv, a[3] * iv);
                *(float4*)&xms[nb][KS + l * 16 + 4] = make_float4(a[4] * iv, a[5] * iv, a[6] * iv, a[7] * iv);
                *(float4*)&xms[nb][KS + l * 16 + 8] = make_float4(a[8] * iv, a[9] * iv, a[10] * iv, a[11] * iv);
                *(float4*)&xms[nb][KS + l * 16 + 12] = make_float4(a[12] * iv, a[13] * iv, a[14] * iv, a[15] * iv);
            }
        } else {
            const int sub = tid & 15;
            const int l = sub & 3;          // uint4 index (4/row)
            const int h = sub >> 2;         // 4 chains
            int e = start + h;
            for (; e + 4 < end; e += 8) {
                int i0 = ssrc[e], i1 = ssrc[e + 4];
                uint4 v0 = xb4[(size_t)i0 * 4 + l];
                uint4 v1 = xb4[(size_t)i1 * 4 + l];
                bacc16(a, v0);
                bacc16(a, v1);
            }
            if (e < end) bacc16(a, xb4[(size_t)ssrc[e] * 4 + l]);
#pragma unroll
            for (int j = 0; j < 16; j++) a[j] += __shfl_xor(a[j], 4);
#pragma unroll
            for (int j = 0; j < 16; j++) a[j] += __shfl_xor(a[j], 8);
            if (h == 0) {
                float iv = 1.0f / fmaxf((float)(end - start), 1.0f);
                *(float4*)&xms[nb][KS + l * 16 + 0] = make_float4(a[0] * iv, a[1] * iv, a[2] * iv, a[3] * iv);
                *(float4*)&xms[nb][KS + l * 16 + 4] = make_float4(a[4] * iv, a[5] * iv, a[6] * iv, a[7] * iv);
                *(float4*)&xms[nb][KS + l * 16 + 8] = make_float4(a[8] * iv, a[9] * iv, a[10] * iv, a[11] * iv);
                *(float4*)&xms[nb][KS + l * 16 + 12] = make_float4(a[12] * iv, a[13] * iv, a[14] * iv, a[15] * iv);
            }
        }
    }
    __syncthreads();

    // ---- GEMM: out = relu([xs|ms] @ [Ws;Wn]) ----
    const int p = tid % 64;
    const int q = tid / 64;
    float a00 = 0, a01 = 0, a10 = 0, a11 = 0, a20 = 0, a21 = 0, a30 = 0, a31 = 0;

#pragma unroll
    for (int seg = 0; seg < 2; seg++) {
        const float* __restrict__ W = seg ? Wn : Ws;
        const int koff = seg * KS;
#pragma unroll 2
        for (int k = 0; k < KS; k += 4) {
            const float* Wk = W + (size_t)k * HID + 2 * p;
            float2 w0 = *(const float2*)(Wk);
            float2 w1 = *(const float2*)(Wk + HID);
            float2 w2 = *(const float2*)(Wk + 2 * HID);
            float2 w3 = *(const float2*)(Wk + 3 * HID);
            float4 v0 = *(const float4*)&xms[4 * q + 0][koff + k];
            float4 v1 = *(const float4*)&xms[4 * q + 1][koff + k];
            float4 v2 = *(const float4*)&xms[4 * q + 2][koff + k];
            float4 v3 = *(const float4*)&xms[4 * q + 3][koff + k];
            a00 += v0.x * w0.x + v0.y * w1.x + v0.z * w2.x + v0.w * w3.x;
            a01 += v0.x * w0.y + v0.y * w1.y + v0.z * w2.y + v0.w * w3.y;
            a10 += v1.x * w0.x + v1.y * w1.x + v1.z * w2.x + v1.w * w3.x;
            a11 += v1.x * w0.y + v1.y * w1.y + v1.z * w2.y + v1.w * w3.y;
            a20 += v2.x * w0.x + v2.y * w1.x + v2.z * w2.x + v2.w * w3.x;
            a21 += v2.x * w0.y + v2.y * w1.y + v2.z * w2.y + v2.w * w3.y;
            a30 += v3.x * w0.x + v3.y * w1.x + v3.z * w2.x + v3.w * w3.x;
            a31 += v3.x * w0.y + v3.y * w1.y + v3.z * w2.y + v3.w * w3.y;
        }
    }

    if constexpr (!REDUCE) {
        unsigned short* o8 = (unsigned short*)outH8;
        float r0, r1;
        r0 = fmaxf(a00, 0.f); r1 = fmaxf(a01, 0.f);
        outHb[(size_t)(n0 + 4 * q + 0) * 64 + p] = (unsigned)f2b(r0) | ((unsigned)f2b(r1) << 16);
        o8[(size_t)(n0 + 4 * q + 0) * 64 + p] = (unsigned short)pk8<false>(r0, r1, 0u);
        r0 = fmaxf(a10, 0.f); r1 = fmaxf(a11, 0.f);
        outHb[(size_t)(n0 + 4 * q + 1) * 64 + p] = (unsigned)f2b(r0) | ((unsigned)f2b(r1) << 16);
        o8[(size_t)(n0 + 4 * q + 1) * 64 + p] = (unsigned short)pk8<false>(r0, r1, 0u);
        r0 = fmaxf(a20, 0.f); r1 = fmaxf(a21, 0.f);
        outHb[(size_t)(n0 + 4 * q + 2) * 64 + p] = (unsigned)f2b(r0) | ((unsigned)f2b(r1) << 16);
        o8[(size_t)(n0 + 4 * q + 2) * 64 + p] = (unsigned short)pk8<false>(r0, r1, 0u);
        r0 = fmaxf(a30, 0.f); r1 = fmaxf(a31, 0.f);
        outHb[(size_t)(n0 + 4 * q + 3) * 64 + p] = (unsigned)f2b(r0) | ((unsigned)f2b(r1) << 16);
        o8[(size_t)(n0 + 4 * q + 3) * 64 + p] = (unsigned short)pk8<false>(r0, r1, 0u);
    } else {
        float s0 = fmaxf(a00, 0.f) + fmaxf(a10, 0.f) + fmaxf(a20, 0.f) + fmaxf(a30, 0.f);
        float s1 = fmaxf(a01, 0.f) + fmaxf(a11, 0.f) + fmaxf(a21, 0.f) + fmaxf(a31, 0.f);
        *(float2*)&part[q][2 * p] = make_float2(s0, s1);
        __syncthreads();
        if (tid < 128) {
            float s = part[0][tid] + part[1][tid] + part[2][tid] + part[3][tid];
            outR[(size_t)blockIdx.x * 128 + tid] = s;
        }
    }
}

// ---------------------------------------------------------------------------
__global__ void reduce1_kernel(const float* __restrict__ p0, const float* __restrict__ p1,
                               float* __restrict__ p2) {
    const int bb = blockIdx.x;
    const int tid = threadIdx.x;
    const int g = tid >> 7;
    const int col = tid & 127;
    const float* p = g ? p1 : p0;
    const int per = GEMMB / RBLK;
    float s = 0.0f;
    for (int r = 0; r < per; r++) s += p[(size_t)(bb * per + r) * 128 + col];
    p2[(size_t)bb * 256 + tid] = s;
}

__global__ void final_kernel(const float* __restrict__ p2,
                             const float* __restrict__ Wlin1,
                             const float* __restrict__ Wlin2,
                             float* __restrict__ out) {
    __shared__ float rep[2][HID];
    __shared__ float sg[32];
    const int tid = threadIdx.x;
    float s = 0.0f;
    for (int r = 0; r < RBLK; r++) s += p2[r * 256 + tid];
    rep[tid >> 7][tid & 127] = s * (1.0f / (float)NN);
    __syncthreads();
    if (tid < 32) {
        const int g = tid / 16;
        const int c = tid % 16;
        const float* W = g ? Wlin2 : Wlin1;
        float a = 0.0f;
        for (int k = 0; k < HID; k++) a += rep[g][k] * W[k * NCLS + c];
        sg[tid] = 1.0f / (1.0f + expf(-a));
    }
    __syncthreads();
    if (tid < 16) out[tid] = 0.5f * (sg[tid] + sg[16 + tid]);
}

// ---------------------------------------------------------------------------
extern "C" void kernel_launch(void* const* d_in, const int* in_sizes, int n_in,
                              void* d_out, int out_size, void* d_ws, size_t ws_size,
                              hipStream_t stream) {
    const float* feats = (const float*)d_in[0];
    const int* srcp[2] = {(const int*)d_in[1], (const int*)d_in[3]};
    const int* dstp[2] = {(const int*)d_in[2], (const int*)d_in[4]};
    const float* Ws1[2] = {(const float*)d_in[5], (const float*)d_in[10]};
    const float* Wn1[2] = {(const float*)d_in[6], (const float*)d_in[11]};
    const float* Ws2[2] = {(const float*)d_in[7], (const float*)d_in[12]};
    const float* Wn2[2] = {(const float*)d_in[8], (const float*)d_in[13]};
    const float* Wlin[2] = {(const float*)d_in[9], (const float*)d_in[14]};

    // workspace layout (~78 MB), 16B-aligned sections
    char* w = (char*)d_ws;
    unsigned* fb8 = (unsigned*)w;   w += (size_t)NN * IND;          // feats fp8
    unsigned* h1b = (unsigned*)w;   w += (size_t)NN * HID * 2;      // h1 bf16
    unsigned* h18 = (unsigned*)w;   w += (size_t)NN * HID;          // h1 fp8
    float* part0 = (float*)w;       w += (size_t)GEMMB * 128 * 4;
    float* part1 = (float*)w;       w += (size_t)GEMMB * 128 * 4;
    float* p2 = (float*)w;          w += (size_t)RBLK * 256 * 4;
    unsigned* pr0 = (unsigned*)w;   w += (size_t)NE * 4;
    unsigned* pr1 = (unsigned*)w;   w += (size_t)NE * 4;
    int* ss0 = (int*)w;             w += (size_t)NE * 4;
    int* ss1 = (int*)w;             w += (size_t)NE * 4;
    int* row0 = (int*)w;            w += (size_t)NN * 4;
    int* row1 = (int*)w;            w += (size_t)NN * 4;
    int* bcnt = (int*)w;            w += 2 * BK * 4;
    int* bbase = (int*)w;           w += 2 * (BK + 1) * 4;
    int* bcur = (int*)w;            w += 2 * BK * 4;

    // feats -> fp8 table
    conv8_kernel<<<(NN * IND / 4 + 255) / 256, 256, 0, stream>>>(
        (const float4*)feats, fb8, NN * IND / 4);

    // bucketed CSR build, both graphs
    (void)hipMemsetAsync(bcnt, 0, 2 * BK * 4, stream);
    bucket_hist<<<2 * NBG, 256, 0, stream>>>(dstp[0], dstp[1], bcnt);
    bucket_scan<<<1, 64, 0, stream>>>(bcnt, bbase, bcur);
    bucket_place<<<2 * NBG, 256, 0, stream>>>(srcp[0], dstp[0], srcp[1], dstp[1],
                                              bcur, pr0, pr1);
    bucket_final<<<2 * BK, 256, 0, stream>>>(pr0, pr1, bbase, row0, row1, ss0, ss1);

    const int* ssg[2] = {ss0, ss1};
    const int* rowg[2] = {row0, row1};
    float* partG[2] = {part0, part1};

    for (int g = 0; g < 2; g++) {
        sage_fused<IND, false><<<GEMMB, 256, 0, stream>>>(
            feats, nullptr, fb8, ssg[g], rowg[g], Ws1[g], Wn1[g], nullptr, h1b, h18);
        sage_fused<HID, true><<<GEMMB, 256, 0, stream>>>(
            nullptr, h1b, h18, ssg[g], rowg[g], Ws2[g], Wn2[g], partG[g], nullptr, nullptr);
    }

    reduce1_kernel<<<RBLK, 256, 0, stream>>>(part0, part1, p2);
    final_kernel<<<1, 256, 0, stream>>>(p2, Wlin[0], Wlin[1], (float*)d_out);
}